// Round 3
// baseline (18333.882 us; speedup 1.0000x reference)
//
#include <hip/hip_runtime.h>

#define BATCH 4096
#define SEQ   200
#define HID   128
#define N3    384   // 3*HID
#define ROWS  8     // batch rows per block
#define NTHREADS 512
#define KT    64    // K-slice per thread (2 slices cover K=128)

// Persistent weight-stationary GRU scan.
// Thread layout: cg = tid & 255 (column-group, 3 cols each over combined 768
// columns: [0,384) = x-projection (kernel), [384,768) = h-projection
// (rec_kernel)); sl = tid >> 8 (K-slice 0/1). Weights (3 cols x 64 k) stay in
// VGPRs for all 200 steps.
// __launch_bounds__(512, 2): 2 waves/EU = one block/CU -> VGPR cap 256, so the
// 192 weight floats stay register-resident (round-2 run at cap 128 spilled
// them to scratch -> 55 GB of HBM scratch traffic, 18 ms).
__global__ __launch_bounds__(NTHREADS, 2) void gru_fused(
    const int* __restrict__ inputs,
    const float* __restrict__ emb,
    const float* __restrict__ kernel,
    const float* __restrict__ rec_kernel,
    const float* __restrict__ bias,
    float* __restrict__ out)
{
    __shared__ float x_lds[ROWS][HID];
    __shared__ float h_lds[ROWS][HID];
    __shared__ float xpart[2][ROWS][N3];
    __shared__ float hpart[2][ROWS][N3];
    __shared__ int tok_sh[ROWS];
    __shared__ int ts_sh;

    const int tid = threadIdx.x;
    const int row0 = blockIdx.x * ROWS;
    const int cg  = tid & 255;
    const int sl  = tid >> 8;
    const bool isx = (cg < 128);
    const int cc  = 3 * cg - (isx ? 0 : N3);   // column base within [0,384)
    const float* W = isx ? kernel : rec_kernel;

    // --- detect token word-stride from data (int32 vs int64 tokens).
    // int64 little-endian: every odd 32-bit word is a zero high half.
    if (tid == 0) {
        int any = 0;
        for (int i = 1; i < 128; i += 2) any |= inputs[i];
        ts_sh = any ? 1 : 2;
    }

    // --- one-time: load this thread's weights into registers ---
    float w0[KT], w1[KT], w2[KT];
#pragma unroll
    for (int k = 0; k < KT; ++k) {
        const float* wp = W + (size_t)(sl * KT + k) * N3 + cc;
        w0[k] = wp[0]; w1[k] = wp[1]; w2[k] = wp[2];
    }
    // bias: baked into slice-0 accumulators only
    float b0 = 0.f, b1 = 0.f, b2 = 0.f;
    if (sl == 0) {
        const float* bp = bias + (isx ? 0 : N3) + cc;
        b0 = bp[0]; b1 = bp[1]; b2 = bp[2];
    }

    // zero h
    for (int idx = tid; idx < ROWS * HID; idx += NTHREADS)
        ((float*)h_lds)[idx] = 0.f;

    float* pout = isx ? &xpart[sl][0][0] : &hpart[sl][0][0];
    const float* xin = isx ? &x_lds[0][0] : &h_lds[0][0];
    const int kofs = sl * KT;

    __syncthreads();            // ts_sh + h_lds ready
    const int ts = ts_sh;

    for (int s = 0; s < SEQ; ++s) {
        __syncthreads();   // h from prev gate ready; x buffer free
        // --- gather embedding rows for this step ---
        for (int idx = tid; idx < ROWS * HID; idx += NTHREADS) {
            const int r = idx >> 7, kk = idx & 127;
            const int tok = inputs[((size_t)(row0 + r) * SEQ + s) * ts];
            if (kk == 0) tok_sh[r] = tok;
            x_lds[r][kk] = emb[(size_t)tok * HID + kk];
        }
        __syncthreads();   // x + tok_sh ready
        // --- partial projections: acc over this thread's K-slice ---
#pragma unroll
        for (int r = 0; r < ROWS; ++r) {
            float a0 = b0, a1 = b1, a2 = b2;
            const float* xr = xin + r * HID + kofs;
#pragma unroll
            for (int kg = 0; kg < KT; kg += 4) {
                const float4 xv = *(const float4*)(xr + kg);
                a0 += xv.x * w0[kg];     a1 += xv.x * w1[kg];     a2 += xv.x * w2[kg];
                a0 += xv.y * w0[kg + 1]; a1 += xv.y * w1[kg + 1]; a2 += xv.y * w2[kg + 1];
                a0 += xv.z * w0[kg + 2]; a1 += xv.z * w1[kg + 2]; a2 += xv.z * w2[kg + 2];
                a0 += xv.w * w0[kg + 3]; a1 += xv.w * w1[kg + 3]; a2 += xv.w * w2[kg + 3];
            }
            pout[r * N3 + cc + 0] = a0;
            pout[r * N3 + cc + 1] = a1;
            pout[r * N3 + cc + 2] = a2;
        }
        __syncthreads();   // partials ready
        // --- gates + h update ---
        for (int p = tid; p < ROWS * HID; p += NTHREADS) {
            const int r = p >> 7, j = p & 127;
            const float xz = xpart[0][r][j]           + xpart[1][r][j];
            const float xr_ = xpart[0][r][HID + j]    + xpart[1][r][HID + j];
            const float xh = xpart[0][r][2 * HID + j] + xpart[1][r][2 * HID + j];
            const float hz = hpart[0][r][j]           + hpart[1][r][j];
            const float hr_ = hpart[0][r][HID + j]    + hpart[1][r][HID + j];
            const float hhr = hpart[0][r][2 * HID + j] + hpart[1][r][2 * HID + j];
            const float z  = 1.f / (1.f + __expf(-(xz + hz)));
            const float rg = 1.f / (1.f + __expf(-(xr_ + hr_)));
            const float e  = __expf(2.f * (xh + rg * hhr));
            const float hh = 1.f - 2.f / (e + 1.f);   // tanh
            const float hold = h_lds[r][j];
            const float hn = z * hold + (1.f - z) * hh;
            h_lds[r][j] = (tok_sh[r] != 0) ? hn : hold;
        }
    }
    __syncthreads();
    for (int idx = tid; idx < ROWS * HID; idx += NTHREADS) {
        const int r = idx >> 7, kk = idx & 127;
        out[(size_t)(row0 + r) * HID + kk] = h_lds[r][kk];
    }
}

extern "C" void kernel_launch(void* const* d_in, const int* in_sizes, int n_in,
                              void* d_out, int out_size, void* d_ws, size_t ws_size,
                              hipStream_t stream) {
    const int* inputs      = (const int*)d_in[0];
    const float* emb       = (const float*)d_in[1];
    const float* kernel    = (const float*)d_in[2];
    const float* rec_k     = (const float*)d_in[3];
    const float* bias      = (const float*)d_in[4];
    float* out             = (float*)d_out;
    gru_fused<<<BATCH / ROWS, NTHREADS, 0, stream>>>(inputs, emb, kernel, rec_k, bias, out);
}

// Round 4
// 16867.776 us; speedup vs baseline: 1.0869x; 1.0869x over previous
//
#include <hip/hip_runtime.h>

#define BATCH 4096
#define SEQ   200
#define HID   128
#define N3    384   // 3*HID
#define ROWS  8     // batch rows per block
#define NTHREADS 512
#define KT    64    // K-slice per thread (2 slices cover K=128)

// Persistent weight-stationary GRU scan.
// Thread layout: cg = tid & 255 (column-group, 3 cols each over combined 768
// columns: [0,384) = x-projection (kernel), [384,768) = h-projection
// (rec_kernel)); sl = tid >> 8 (K-slice 0/1). Weights (3 cols x 64 k) stay in
// VGPRs for all 200 steps.
// amdgpu_waves_per_eu(2,2): pin the allocator's occupancy TARGET to 2
// waves/EU -> 256-VGPR budget. launch_bounds(512,2) only set a minimum
// (=VGPR ceiling); the allocator still targeted 4 waves/EU and spilled all
// 192 weight floats to scratch (rounds 2-3: VGPR_Count=128, 55 GB scratch
// reads, 18 ms).
__global__ __attribute__((amdgpu_flat_work_group_size(NTHREADS, NTHREADS),
                          amdgpu_waves_per_eu(2, 2)))
void gru_fused(
    const int* __restrict__ inputs,
    const float* __restrict__ emb,
    const float* __restrict__ kernel,
    const float* __restrict__ rec_kernel,
    const float* __restrict__ bias,
    float* __restrict__ out)
{
    __shared__ float x_lds[ROWS][HID];
    __shared__ float h_lds[ROWS][HID];
    __shared__ float xpart[2][ROWS][N3];
    __shared__ float hpart[2][ROWS][N3];
    __shared__ int tok_sh[ROWS];
    __shared__ int ts_sh;

    const int tid = threadIdx.x;
    const int row0 = blockIdx.x * ROWS;
    const int cg  = tid & 255;
    const int sl  = tid >> 8;
    const bool isx = (cg < 128);
    const int cc  = 3 * cg - (isx ? 0 : N3);   // column base within [0,384)
    const float* W = isx ? kernel : rec_kernel;

    // --- detect token word-stride from data (int32 vs int64 tokens).
    // int64 little-endian: every odd 32-bit word is a zero high half.
    if (tid == 0) {
        int any = 0;
        for (int i = 1; i < 128; i += 2) any |= inputs[i];
        ts_sh = any ? 1 : 2;
    }

    // --- one-time: load this thread's weights into registers ---
    float w0[KT], w1[KT], w2[KT];
#pragma unroll
    for (int k = 0; k < KT; ++k) {
        const float* wp = W + (size_t)(sl * KT + k) * N3 + cc;
        w0[k] = wp[0]; w1[k] = wp[1]; w2[k] = wp[2];
    }
    // bias: baked into slice-0 accumulators only
    float b0 = 0.f, b1 = 0.f, b2 = 0.f;
    if (sl == 0) {
        const float* bp = bias + (isx ? 0 : N3) + cc;
        b0 = bp[0]; b1 = bp[1]; b2 = bp[2];
    }

    // zero h
    for (int idx = tid; idx < ROWS * HID; idx += NTHREADS)
        ((float*)h_lds)[idx] = 0.f;

    float* pout = isx ? &xpart[sl][0][0] : &hpart[sl][0][0];
    const float* xin = isx ? &x_lds[0][0] : &h_lds[0][0];
    const int kofs = sl * KT;

    __syncthreads();            // ts_sh + h_lds ready
    const int ts = ts_sh;

    for (int s = 0; s < SEQ; ++s) {
        __syncthreads();   // h from prev gate ready; x buffer free
        // --- gather embedding rows for this step ---
        for (int idx = tid; idx < ROWS * HID; idx += NTHREADS) {
            const int r = idx >> 7, kk = idx & 127;
            const int tok = inputs[((size_t)(row0 + r) * SEQ + s) * ts];
            if (kk == 0) tok_sh[r] = tok;
            x_lds[r][kk] = emb[(size_t)tok * HID + kk];
        }
        __syncthreads();   // x + tok_sh ready
        // --- partial projections: acc over this thread's K-slice ---
#pragma unroll
        for (int r = 0; r < ROWS; ++r) {
            float a0 = b0, a1 = b1, a2 = b2;
            const float* xr = xin + r * HID + kofs;
#pragma unroll
            for (int kg = 0; kg < KT; kg += 4) {
                const float4 xv = *(const float4*)(xr + kg);
                a0 += xv.x * w0[kg];     a1 += xv.x * w1[kg];     a2 += xv.x * w2[kg];
                a0 += xv.y * w0[kg + 1]; a1 += xv.y * w1[kg + 1]; a2 += xv.y * w2[kg + 1];
                a0 += xv.z * w0[kg + 2]; a1 += xv.z * w1[kg + 2]; a2 += xv.z * w2[kg + 2];
                a0 += xv.w * w0[kg + 3]; a1 += xv.w * w1[kg + 3]; a2 += xv.w * w2[kg + 3];
            }
            pout[r * N3 + cc + 0] = a0;
            pout[r * N3 + cc + 1] = a1;
            pout[r * N3 + cc + 2] = a2;
        }
        __syncthreads();   // partials ready
        // --- gates + h update ---
        for (int p = tid; p < ROWS * HID; p += NTHREADS) {
            const int r = p >> 7, j = p & 127;
            const float xz = xpart[0][r][j]           + xpart[1][r][j];
            const float xr_ = xpart[0][r][HID + j]    + xpart[1][r][HID + j];
            const float xh = xpart[0][r][2 * HID + j] + xpart[1][r][2 * HID + j];
            const float hz = hpart[0][r][j]           + hpart[1][r][j];
            const float hr_ = hpart[0][r][HID + j]    + hpart[1][r][HID + j];
            const float hhr = hpart[0][r][2 * HID + j] + hpart[1][r][2 * HID + j];
            const float z  = 1.f / (1.f + __expf(-(xz + hz)));
            const float rg = 1.f / (1.f + __expf(-(xr_ + hr_)));
            const float e  = __expf(2.f * (xh + rg * hhr));
            const float hh = 1.f - 2.f / (e + 1.f);   // tanh
            const float hold = h_lds[r][j];
            const float hn = z * hold + (1.f - z) * hh;
            h_lds[r][j] = (tok_sh[r] != 0) ? hn : hold;
        }
    }
    __syncthreads();
    for (int idx = tid; idx < ROWS * HID; idx += NTHREADS) {
        const int r = idx >> 7, kk = idx & 127;
        out[(size_t)(row0 + r) * HID + kk] = h_lds[r][kk];
    }
}

extern "C" void kernel_launch(void* const* d_in, const int* in_sizes, int n_in,
                              void* d_out, int out_size, void* d_ws, size_t ws_size,
                              hipStream_t stream) {
    const int* inputs      = (const int*)d_in[0];
    const float* emb       = (const float*)d_in[1];
    const float* kernel    = (const float*)d_in[2];
    const float* rec_k     = (const float*)d_in[3];
    const float* bias      = (const float*)d_in[4];
    float* out             = (float*)d_out;
    gru_fused<<<BATCH / ROWS, NTHREADS, 0, stream>>>(inputs, emb, kernel, rec_k, bias, out);
}

// Round 5
// 14265.388 us; speedup vs baseline: 1.2852x; 1.1824x over previous
//
#include <hip/hip_runtime.h>

#define BATCH 4096
#define SEQ   200
#define HID   128
#define N3    384   // 3*HID
#define ROWS  8     // batch rows per block
#define NTHREADS 1024
#define KT    32    // K-slice per thread (4 slices cover K=128)
#define NSL   4

// Persistent weight-stationary GRU scan, v2: sized to fit under the 128-VGPR
// default cap (rounds 2-4 proved the allocator refuses >128 VGPRs here and
// spills: 52 GB scratch traffic, 17-18 ms).
// 1024 threads/block: cg = tid & 255 -> 3 columns of the combined 768
// ([0,384)=x-proj via kernel, [384,768)=h-proj via rec_kernel);
// sl = tid >> 8 -> one of 4 K-slices of 32. Per-thread weights = 3x32 = 96
// floats, register-resident for all 200 steps. Partial sums land in LDS
// ([4][ROWS][384] x 2 = 98 KB); gate phase reduces 4 slices + applies
// sigmoid/tanh/mask.
__global__ __attribute__((amdgpu_flat_work_group_size(NTHREADS, NTHREADS)))
void gru_fused(
    const int* __restrict__ inputs,
    const float* __restrict__ emb,
    const float* __restrict__ kernel,
    const float* __restrict__ rec_kernel,
    const float* __restrict__ bias,
    float* __restrict__ out)
{
    __shared__ float x_lds[ROWS][HID];
    __shared__ float h_lds[ROWS][HID];
    __shared__ float xpart[NSL][ROWS][N3];
    __shared__ float hpart[NSL][ROWS][N3];
    __shared__ int tok_sh[ROWS];
    __shared__ int ts_sh;

    const int tid = threadIdx.x;
    const int row0 = blockIdx.x * ROWS;
    const int cg  = tid & 255;
    const int sl  = tid >> 8;
    const bool isx = (cg < 128);
    const int cc  = 3 * cg - (isx ? 0 : N3);   // column base within [0,384)
    const float* W = isx ? kernel : rec_kernel;

    // --- detect token word-stride from data (int32 vs int64 tokens).
    // int64 little-endian: every odd 32-bit word is a zero high half.
    if (tid == 0) {
        int any = 0;
        for (int i = 1; i < 128; i += 2) any |= inputs[i];
        ts_sh = any ? 1 : 2;
    }

    // --- one-time: load this thread's weights into registers (96 floats) ---
    float w0[KT], w1[KT], w2[KT];
#pragma unroll
    for (int k = 0; k < KT; ++k) {
        const float* wp = W + (size_t)(sl * KT + k) * N3 + cc;
        w0[k] = wp[0]; w1[k] = wp[1]; w2[k] = wp[2];
    }
    // bias: baked into slice-0 accumulators only
    float b0 = 0.f, b1 = 0.f, b2 = 0.f;
    if (sl == 0) {
        const float* bp = bias + (isx ? 0 : N3) + cc;
        b0 = bp[0]; b1 = bp[1]; b2 = bp[2];
    }

    // zero h
    if (tid < ROWS * HID) ((float*)h_lds)[tid] = 0.f;

    float* pout = isx ? &xpart[sl][0][0] : &hpart[sl][0][0];
    const float* xin = isx ? &x_lds[0][0] : &h_lds[0][0];
    const int kofs = sl * KT;

    __syncthreads();            // ts_sh + h_lds ready
    const int ts = ts_sh;

    for (int s = 0; s < SEQ; ++s) {
        __syncthreads();   // h from prev gate ready; x buffer free
        // --- gather embedding rows for this step (1 elem/thread) ---
        if (tid < ROWS * HID) {
            const int r = tid >> 7, kk = tid & 127;
            const int tok = inputs[((size_t)(row0 + r) * SEQ + s) * ts];
            if (kk == 0) tok_sh[r] = tok;
            x_lds[r][kk] = emb[(size_t)tok * HID + kk];
        }
        __syncthreads();   // x + tok_sh ready
        // --- partial projections: acc over this thread's 32-wide K-slice ---
#pragma unroll
        for (int r = 0; r < ROWS; ++r) {
            float a0 = b0, a1 = b1, a2 = b2;
            const float* xr = xin + r * HID + kofs;
#pragma unroll
            for (int kg = 0; kg < KT; kg += 4) {
                const float4 xv = *(const float4*)(xr + kg);
                a0 += xv.x * w0[kg];     a1 += xv.x * w1[kg];     a2 += xv.x * w2[kg];
                a0 += xv.y * w0[kg + 1]; a1 += xv.y * w1[kg + 1]; a2 += xv.y * w2[kg + 1];
                a0 += xv.z * w0[kg + 2]; a1 += xv.z * w1[kg + 2]; a2 += xv.z * w2[kg + 2];
                a0 += xv.w * w0[kg + 3]; a1 += xv.w * w1[kg + 3]; a2 += xv.w * w2[kg + 3];
            }
            pout[r * N3 + cc + 0] = a0;
            pout[r * N3 + cc + 1] = a1;
            pout[r * N3 + cc + 2] = a2;
        }
        __syncthreads();   // partials ready
        // --- gates + h update (1 elem/thread) ---
        if (tid < ROWS * HID) {
            const int r = tid >> 7, j = tid & 127;
            float xz = 0.f, xr_ = 0.f, xh = 0.f, hz = 0.f, hr_ = 0.f, hhr = 0.f;
#pragma unroll
            for (int q = 0; q < NSL; ++q) {
                xz  += xpart[q][r][j];
                xr_ += xpart[q][r][HID + j];
                xh  += xpart[q][r][2 * HID + j];
                hz  += hpart[q][r][j];
                hr_ += hpart[q][r][HID + j];
                hhr += hpart[q][r][2 * HID + j];
            }
            const float z  = 1.f / (1.f + __expf(-(xz + hz)));
            const float rg = 1.f / (1.f + __expf(-(xr_ + hr_)));
            const float e  = __expf(2.f * (xh + rg * hhr));
            const float hh = 1.f - 2.f / (e + 1.f);   // tanh
            const float hold = h_lds[r][j];
            const float hn = z * hold + (1.f - z) * hh;
            h_lds[r][j] = (tok_sh[r] != 0) ? hn : hold;
        }
    }
    __syncthreads();
    if (tid < ROWS * HID) {
        const int r = tid >> 7, kk = tid & 127;
        out[(size_t)(row0 + r) * HID + kk] = h_lds[r][kk];
    }
}

extern "C" void kernel_launch(void* const* d_in, const int* in_sizes, int n_in,
                              void* d_out, int out_size, void* d_ws, size_t ws_size,
                              hipStream_t stream) {
    const int* inputs      = (const int*)d_in[0];
    const float* emb       = (const float*)d_in[1];
    const float* kernel    = (const float*)d_in[2];
    const float* rec_k     = (const float*)d_in[3];
    const float* bias      = (const float*)d_in[4];
    float* out             = (float*)d_out;
    gru_fused<<<BATCH / ROWS, NTHREADS, 0, stream>>>(inputs, emb, kernel, rec_k, bias, out);
}

// Round 7
// 2603.494 us; speedup vs baseline: 7.0420x; 5.4793x over previous
//
#include <hip/hip_runtime.h>
#include <hip/hip_fp16.h>

#define BATCH 4096
#define SEQ   200
#define HID   128
#define N3    384   // 3*HID
#define ROWS  8     // batch rows per block
#define NTHREADS 512
#define KT    64    // K-slice per thread (2 slices cover K=128)
#define NSL   2

// Persistent weight-stationary GRU scan, v3: weights held as fp16 PAIRS in
// 96 VGPRs per thread (rounds 2-5 proved fp32 residency is impossible: the
// allocator budgets 128 VGPRs @512thr / 64 @1024thr and rematerializes
// weight loads from global every step -> 43-55 GB fabric traffic at
// ~3.2 TB/s = 14-18 ms). fp32 x/h + fp32 accumulate; fp16 only on weights
// (|w|<~0.6, rel err 4.9e-4 -> est total ~1e-3 < 3.4e-3 threshold).
// Thread layout: cg = tid & 255 -> 3 columns of combined 768
// ([0,384)=x-proj/kernel, [384,768)=h-proj/rec_kernel); sl = tid>>8 -> k-half.
__global__ __attribute__((amdgpu_flat_work_group_size(NTHREADS, NTHREADS)))
void gru_fused(
    const int* __restrict__ inputs,
    const float* __restrict__ emb,
    const float* __restrict__ kernel,
    const float* __restrict__ rec_kernel,
    const float* __restrict__ bias,
    float* __restrict__ out)
{
    __shared__ float x_lds[ROWS][HID];
    __shared__ float h_lds[ROWS][HID];
    __shared__ float xpart[NSL][ROWS][N3];
    __shared__ float hpart[NSL][ROWS][N3];
    __shared__ float bias_sh[2 * N3];
    __shared__ int tok_sh[ROWS];
    __shared__ int ts_sh;

    const int tid = threadIdx.x;
    const int row0 = blockIdx.x * ROWS;
    const int cg  = tid & 255;
    const int sl  = tid >> 8;
    const bool isx = (cg < 128);
    const int cc  = 3 * cg - (isx ? 0 : N3);   // column base within [0,384)
    const float* W = isx ? kernel : rec_kernel;

    // token word-stride detection (int32 vs int64 input), data-driven:
    // int64 LE tokens < 2^31 have zero odd words.
    if (tid == 0) {
        int any = 0;
        for (int i = 1; i < 128; i += 2) any |= inputs[i];
        ts_sh = any ? 1 : 2;
    }
    // stage biases in LDS (gate phase reads them; keeps hot loop lean)
    for (int i = tid; i < 2 * N3; i += NTHREADS) bias_sh[i] = bias[i];

    // --- one-time: load + pack this thread's weights into 96 VGPRs ---
    // w{0,1,2}[k2] holds (k = kbase+2*k2, kbase+2*k2+1) as (lo, hi) fp16.
    __half2 w0[KT / 2], w1[KT / 2], w2[KT / 2];
    const int kbase = sl * KT;
#pragma unroll
    for (int k2 = 0; k2 < KT / 2; ++k2) {
        const float* wp0 = W + (size_t)(kbase + 2 * k2) * N3 + cc;
        const float* wp1 = wp0 + N3;
        w0[k2] = __floats2half2_rn(wp0[0], wp1[0]);
        w1[k2] = __floats2half2_rn(wp0[1], wp1[1]);
        w2[k2] = __floats2half2_rn(wp0[2], wp1[2]);
    }

    // zero h
    for (int idx = tid; idx < ROWS * HID; idx += NTHREADS)
        ((float*)h_lds)[idx] = 0.f;

    float* pout = isx ? &xpart[sl][0][0] : &hpart[sl][0][0];
    const float* xin = isx ? &x_lds[0][0] : &h_lds[0][0];

    __syncthreads();            // ts_sh + bias_sh + h_lds ready
    const int ts = ts_sh;

    for (int s = 0; s < SEQ; ++s) {
        __syncthreads();   // h from prev gate ready; x buffer free
        // --- gather embedding rows for this step ---
        for (int idx = tid; idx < ROWS * HID; idx += NTHREADS) {
            const int r = idx >> 7, kk = idx & 127;
            const int tok = inputs[((size_t)(row0 + r) * SEQ + s) * ts];
            if (kk == 0) tok_sh[r] = tok;
            x_lds[r][kk] = emb[(size_t)tok * HID + kk];
        }
        __syncthreads();   // x + tok_sh ready
        // --- partial projections over this thread's 64-wide K-slice ---
#pragma unroll
        for (int r = 0; r < ROWS; ++r) {
            float a0 = 0.f, a1 = 0.f, a2 = 0.f;
            const float* xr = xin + r * HID + kbase;
#pragma unroll
            for (int kq = 0; kq < KT / 4; ++kq) {   // 4 k per iter
                const float4 xv = *(const float4*)(xr + 4 * kq);
                const __half2 p0 = w0[2 * kq],     p1 = w1[2 * kq],     p2 = w2[2 * kq];
                const __half2 q0 = w0[2 * kq + 1], q1 = w1[2 * kq + 1], q2 = w2[2 * kq + 1];
                a0 += xv.x * __low2float(p0);  a1 += xv.x * __low2float(p1);  a2 += xv.x * __low2float(p2);
                a0 += xv.y * __high2float(p0); a1 += xv.y * __high2float(p1); a2 += xv.y * __high2float(p2);
                a0 += xv.z * __low2float(q0);  a1 += xv.z * __low2float(q1);  a2 += xv.z * __low2float(q2);
                a0 += xv.w * __high2float(q0); a1 += xv.w * __high2float(q1); a2 += xv.w * __high2float(q2);
            }
            pout[r * N3 + cc + 0] = a0;
            pout[r * N3 + cc + 1] = a1;
            pout[r * N3 + cc + 2] = a2;
        }
        __syncthreads();   // partials ready
        // --- gates + h update (2 elems/thread) ---
        for (int p = tid; p < ROWS * HID; p += NTHREADS) {
            const int r = p >> 7, j = p & 127;
            const float xz = xpart[0][r][j]            + xpart[1][r][j]            + bias_sh[j];
            const float xr_ = xpart[0][r][HID + j]     + xpart[1][r][HID + j]      + bias_sh[HID + j];
            const float xh = xpart[0][r][2 * HID + j]  + xpart[1][r][2 * HID + j]  + bias_sh[2 * HID + j];
            const float hz = hpart[0][r][j]            + hpart[1][r][j]            + bias_sh[N3 + j];
            const float hr_ = hpart[0][r][HID + j]     + hpart[1][r][HID + j]      + bias_sh[N3 + HID + j];
            const float hhr = hpart[0][r][2 * HID + j] + hpart[1][r][2 * HID + j]  + bias_sh[N3 + 2 * HID + j];
            const float z  = 1.f / (1.f + __expf(-(xz + hz)));
            const float rg = 1.f / (1.f + __expf(-(xr_ + hr_)));
            const float e  = __expf(2.f * (xh + rg * hhr));
            const float hh = 1.f - 2.f / (e + 1.f);   // tanh
            const float hold = h_lds[r][j];
            const float hn = z * hold + (1.f - z) * hh;
            h_lds[r][j] = (tok_sh[r] != 0) ? hn : hold;
        }
    }
    __syncthreads();
    for (int idx = tid; idx < ROWS * HID; idx += NTHREADS) {
        const int r = idx >> 7, kk = idx & 127;
        out[(size_t)(row0 + r) * HID + kk] = h_lds[r][kk];
    }
}

extern "C" void kernel_launch(void* const* d_in, const int* in_sizes, int n_in,
                              void* d_out, int out_size, void* d_ws, size_t ws_size,
                              hipStream_t stream) {
    const int* inputs      = (const int*)d_in[0];
    const float* emb       = (const float*)d_in[1];
    const float* kernel    = (const float*)d_in[2];
    const float* rec_k     = (const float*)d_in[3];
    const float* bias      = (const float*)d_in[4];
    float* out             = (float*)d_out;
    gru_fused<<<BATCH / ROWS, NTHREADS, 0, stream>>>(inputs, emb, kernel, rec_k, bias, out);
}

// Round 9
// 1834.435 us; speedup vs baseline: 9.9943x; 1.4192x over previous
//
#include <hip/hip_runtime.h>

#define BATCH 4096
#define SEQ   200
#define HID   128
#define N3    384   // 3*HID
#define ROWS  8     // batch rows per block
#define NTHREADS 512
#define KT    64    // K-slice per thread (2 slices cover K=128)
#define NSL   2

typedef _Float16 f16;
typedef f16 f16x2 __attribute__((ext_vector_type(2)));
typedef f16 f16x8 __attribute__((ext_vector_type(8)));

#if defined(__has_builtin)
#if __has_builtin(__builtin_amdgcn_fdot2)
#define FDOT2(a, b, c) __builtin_amdgcn_fdot2((a), (b), (c), false)
#endif
#endif
#ifndef FDOT2
#define FDOT2(a, b, c) ((float)(a)[0] * (float)(b)[0] + (float)(a)[1] * (float)(b)[1] + (c))
#endif

// Persistent weight-stationary GRU scan, v4: v_dot2_f32_f16 inner loop.
// Round 7 (fp16 weights, fp32 x/h, scalar fma+cvt) ran 2.6 ms VALU-issue-
// bound: every fp16 weight needed a v_cvt before its v_fma (~2800 ops/
// thread-step). dot2 does 2 MACs per instruction on packed f16 pairs with
// f32 accumulate -> ~900 issue-ops/thread-step. x and h are mirrored to f16
// in LDS for the matmul inputs; the h STATE stays fp32 (rounding enters only
// through the recurrent matmul input, contracted by the z-gate, not the
// carry). Weights: 96 VGPRs of f16x2 per thread, resident (round 7 verified:
// FETCH 204 MB = one-time loads only).
__global__ __attribute__((amdgpu_flat_work_group_size(NTHREADS, NTHREADS)))
void gru_fused(
    const int* __restrict__ inputs,
    const float* __restrict__ emb,
    const float* __restrict__ kernel,
    const float* __restrict__ rec_kernel,
    const float* __restrict__ bias,
    float* __restrict__ out)
{
    __shared__ __align__(16) f16 x16[ROWS][HID];   // f16 mirror of x_t
    __shared__ __align__(16) f16 h16[ROWS][HID];   // f16 mirror of h_{t-1}
    __shared__ float h_lds[ROWS][HID];             // fp32 h state (the carry)
    __shared__ float xpart[NSL][ROWS][N3];
    __shared__ float hpart[NSL][ROWS][N3];
    __shared__ float bias_sh[2 * N3];
    __shared__ int tok_sh[ROWS];
    __shared__ int ts_sh;

    const int tid = threadIdx.x;
    const int row0 = blockIdx.x * ROWS;
    const int cg  = tid & 255;
    const int sl  = tid >> 8;
    const bool isx = (cg < 128);
    const int cc  = 3 * cg - (isx ? 0 : N3);   // column base within [0,384)
    const float* W = isx ? kernel : rec_kernel;

    // token word-stride detection (int32 vs int64 input), data-driven:
    // int64 LE tokens < 2^31 have zero odd words.
    if (tid == 0) {
        int any = 0;
        for (int i = 1; i < 128; i += 2) any |= inputs[i];
        ts_sh = any ? 1 : 2;
    }
    // stage biases in LDS (gate phase reads them)
    for (int i = tid; i < 2 * N3; i += NTHREADS) bias_sh[i] = bias[i];

    // --- one-time: load + pack this thread's weights into 96 VGPRs ---
    // w{0,1,2}[k2] = (w[kbase+2k2], w[kbase+2k2+1]) packed f16 — pairing
    // matches the f16x2 layout of consecutive k in x16/h16.
    f16x2 w0[KT / 2], w1[KT / 2], w2[KT / 2];
    const int kbase = sl * KT;
#pragma unroll
    for (int k2 = 0; k2 < KT / 2; ++k2) {
        const float* wp0 = W + (size_t)(kbase + 2 * k2) * N3 + cc;
        const float* wp1 = wp0 + N3;
        f16x2 t0; t0[0] = (f16)wp0[0]; t0[1] = (f16)wp1[0]; w0[k2] = t0;
        f16x2 t1; t1[0] = (f16)wp0[1]; t1[1] = (f16)wp1[1]; w1[k2] = t1;
        f16x2 t2; t2[0] = (f16)wp0[2]; t2[1] = (f16)wp1[2]; w2[k2] = t2;
    }

    // zero h (fp32 state + f16 mirror)
    for (int idx = tid; idx < ROWS * HID; idx += NTHREADS) {
        ((float*)h_lds)[idx] = 0.f;
        ((f16*)h16)[idx] = (f16)0.f;
    }

    float* pout = isx ? &xpart[sl][0][0] : &hpart[sl][0][0];
    const f16* xin = isx ? &x16[0][0] : &h16[0][0];

    __syncthreads();            // ts_sh + bias_sh + h ready
    const int ts = ts_sh;

    for (int s = 0; s < SEQ; ++s) {
        __syncthreads();   // h/h16 from prev gate ready; x16 buffer free
        // --- gather embedding rows -> f16 (2 elems = 1 f16x2 per thread) ---
        {
            const int r = tid >> 6, j2 = tid & 63;   // 512 thr = 8 rows x 64 pairs
            const int tok = inputs[((size_t)(row0 + r) * SEQ + s) * ts];
            if (j2 == 0) tok_sh[r] = tok;
            const float* ep = emb + (size_t)tok * HID + 2 * j2;
            f16x2 xv; xv[0] = (f16)ep[0]; xv[1] = (f16)ep[1];
            *(f16x2*)&x16[r][2 * j2] = xv;
        }
        __syncthreads();   // x16 + tok_sh ready
        // --- partial projections over this thread's 64-wide K-slice ---
#pragma unroll
        for (int r = 0; r < ROWS; ++r) {
            float a0 = 0.f, a1 = 0.f, a2 = 0.f;
            const f16x8* xr = (const f16x8*)(xin + r * HID + kbase);
#pragma unroll
            for (int kq = 0; kq < KT / 8; ++kq) {   // 8 k per iter, 1 b128 read
                const f16x8 xv = xr[kq];
#pragma unroll
                for (int j = 0; j < 4; ++j) {
                    f16x2 xp; xp[0] = xv[2 * j]; xp[1] = xv[2 * j + 1];
                    const int wi = 4 * kq + j;
                    a0 = FDOT2(xp, w0[wi], a0);
                    a1 = FDOT2(xp, w1[wi], a1);
                    a2 = FDOT2(xp, w2[wi], a2);
                }
            }
            pout[r * N3 + cc + 0] = a0;
            pout[r * N3 + cc + 1] = a1;
            pout[r * N3 + cc + 2] = a2;
        }
        __syncthreads();   // partials ready
        // --- gates + h update (2 elems/thread) ---
        for (int p = tid; p < ROWS * HID; p += NTHREADS) {
            const int r = p >> 7, j = p & 127;
            const float xz = xpart[0][r][j]            + xpart[1][r][j]            + bias_sh[j];
            const float xr_ = xpart[0][r][HID + j]     + xpart[1][r][HID + j]      + bias_sh[HID + j];
            const float xh = xpart[0][r][2 * HID + j]  + xpart[1][r][2 * HID + j]  + bias_sh[2 * HID + j];
            const float hz = hpart[0][r][j]            + hpart[1][r][j]            + bias_sh[N3 + j];
            const float hr_ = hpart[0][r][HID + j]     + hpart[1][r][HID + j]      + bias_sh[N3 + HID + j];
            const float hhr = hpart[0][r][2 * HID + j] + hpart[1][r][2 * HID + j]  + bias_sh[N3 + 2 * HID + j];
            const float z  = 1.f / (1.f + __expf(-(xz + hz)));
            const float rg = 1.f / (1.f + __expf(-(xr_ + hr_)));
            const float e  = __expf(2.f * (xh + rg * hhr));
            const float hh = 1.f - 2.f / (e + 1.f);   // tanh
            const float hold = h_lds[r][j];
            const float hn = z * hold + (1.f - z) * hh;
            const float hm = (tok_sh[r] != 0) ? hn : hold;
            h_lds[r][j] = hm;
            h16[r][j] = (f16)hm;
        }
    }
    __syncthreads();
    for (int idx = tid; idx < ROWS * HID; idx += NTHREADS) {
        const int r = idx >> 7, kk = idx & 127;
        out[(size_t)(row0 + r) * HID + kk] = h_lds[r][kk];
    }
}

extern "C" void kernel_launch(void* const* d_in, const int* in_sizes, int n_in,
                              void* d_out, int out_size, void* d_ws, size_t ws_size,
                              hipStream_t stream) {
    const int* inputs      = (const int*)d_in[0];
    const float* emb       = (const float*)d_in[1];
    const float* kernel    = (const float*)d_in[2];
    const float* rec_k     = (const float*)d_in[3];
    const float* bias      = (const float*)d_in[4];
    float* out             = (float*)d_out;
    gru_fused<<<BATCH / ROWS, NTHREADS, 0, stream>>>(inputs, emb, kernel, rec_k, bias, out);
}

// Round 12
// 341.000 us; speedup vs baseline: 53.7651x; 5.3796x over previous
//
#include <hip/hip_runtime.h>

#define BATCH 4096
#define SEQ   200
#define HID   128
#define ROWS  16
#define NTH   512
#define XPAD  136   // f16 per LDS row: 128 + 8 pad (16B-aligned, bank-skewed)

typedef _Float16 f16;
typedef f16 f16x4 __attribute__((ext_vector_type(4)));
typedef f16 f16x8 __attribute__((ext_vector_type(8)));
typedef float f32x4 __attribute__((ext_vector_type(4)));

#define MFMA(a, b, c) __builtin_amdgcn_mfma_f32_16x16x32_f16((a), (b), (c), 0, 0, 0)

// Persistent GRU, v6: BUILTIN MFMA 16x16x32_f16 (rounds 10/11's raw-asm MFMA
// failed at absmax 7.5e-2 regardless of hazard nops — the builtin path is the
// HW-verified one). Register-pressure split: x-proj B-frags (12 x f16x8 = 48
// regs) stay in registers; rec_kernel lives in LDS PRE-TRANSPOSED f16
// (Wt[col][k], 104 KB) so its 12 B-frags are contiguous ds_read_b128 per
// step — re-reading from LDS each step IS the register-relief mechanism
// (demand ~110 < the 128-VGPR cap rounds 2-5 established; no remat/spill).
// grid 256 x 512thr: block owns 16 batch rows; wave w owns cols [16w,16w+16).
// z,r accumulate x-proj AND h-proj into one C each; gates lane-local in the
// D layout (col=lane&15, row=(lane>>4)*4+reg, m89-verified); h in 4 VGPRs.
__global__ __attribute__((amdgpu_flat_work_group_size(NTH, NTH)))
void gru_mfma(const int* __restrict__ inputs,
              const float* __restrict__ emb,
              const float* __restrict__ kernel,
              const float* __restrict__ rec_kernel,
              const float* __restrict__ bias,
              float* __restrict__ out)
{
    __shared__ __align__(16) f16 Wt[384][XPAD];    // rec_kernel^T (f16)
    __shared__ __align__(16) f16 x16[ROWS][XPAD];  // f16 mirror of x_t
    __shared__ __align__(16) f16 h16[ROWS][XPAD];  // f16 mirror of h_{t-1}
    __shared__ int tok_sh[ROWS];
    __shared__ int ts_sh;

    const int tid  = threadIdx.x;
    const int lane = tid & 63;
    const int j0   = (tid >> 6) * 16;   // wave's column slice
    const int l15  = lane & 15;
    const int hi   = lane >> 4;         // 0..3
    const int r0   = hi * 4;            // D-layout row base
    const int row0 = blockIdx.x * ROWS;

    // int32-vs-int64 token stride, detected from data (int64 LE: odd words 0)
    if (tid == 0) { int any = 0; for (int i = 1; i < 128; i += 2) any |= inputs[i]; ts_sh = any ? 1 : 2; }

    // --- stage rec_kernel^T into LDS (one-time; coalesced global reads) ---
    for (int i = tid; i < 384 * HID; i += NTH) {
        const int c = i % 384, k = i / 384;
        Wt[c][k] = (f16)rec_kernel[(size_t)k * 384 + c];
    }

    // --- one-time: x-proj B fragments in registers (12 x f16x8 = 48 regs) ---
    f16x8 Bx[3][4];   // [gate][ktile]
#pragma unroll
    for (int g = 0; g < 3; ++g)
#pragma unroll
        for (int kt = 0; kt < 4; ++kt) {
            f16x8 t;
#pragma unroll
            for (int e = 0; e < 8; ++e)
                t[e] = (f16)kernel[(size_t)(kt * 32 + hi * 8 + e) * 384 + g * HID + j0 + l15];
            Bx[g][kt] = t;
        }

    // biases for this lane's column (z,r combine input+rec bias; h split)
    const float bz  = bias[j0 + l15]       + bias[384 + j0 + l15];
    const float br  = bias[128 + j0 + l15] + bias[512 + j0 + l15];
    const float bxh = bias[256 + j0 + l15];
    const float brh = bias[640 + j0 + l15];

    f32x4 h = {0.f, 0.f, 0.f, 0.f};     // h state: rows r0..r0+3, col j0+l15

    __syncthreads();
    const int ts = ts_sh;

    const int rr = tid >> 5;            // gather: row 0..15
    const int c4 = (tid & 31) * 4;      // gather: 4-col group

    // --- prologue: stage x for s=0, zero h16, prime token pipeline ---
    {
        const int tok0 = inputs[((size_t)(row0 + rr) * SEQ + 0) * ts];
        if ((tid & 31) == 0) tok_sh[rr] = tok0;
        const float4 ev = *(const float4*)&emb[(size_t)tok0 * HID + c4];
        f16x4 xv; xv[0] = (f16)ev.x; xv[1] = (f16)ev.y; xv[2] = (f16)ev.z; xv[3] = (f16)ev.w;
        *(f16x4*)&x16[rr][c4] = xv;
        for (int i = tid; i < ROWS * XPAD; i += NTH) ((f16*)h16)[i] = (f16)0.f;
    }
    int tokA = inputs[((size_t)(row0 + rr) * SEQ + 1) * ts];   // token for s+1
    __syncthreads();

    for (int s = 0; s < SEQ; ++s) {
        const bool pf = (s + 1 < SEQ);
        float4 ev; int tokB = tokA;
        if (pf) {   // issue next-step gather early; consumed after barrier
            ev = *(const float4*)&emb[(size_t)tokA * HID + c4];
            const int s2 = (s + 2 < SEQ) ? (s + 2) : (SEQ - 1);
            tokB = inputs[((size_t)(row0 + rr) * SEQ + s2) * ts];
        }

        f32x4 az = {bz, bz, bz, bz}, ar = {br, br, br, br};
        f32x4 ax = {bxh, bxh, bxh, bxh}, ah = {brh, brh, brh, brh};
#pragma unroll
        for (int kt = 0; kt < 4; ++kt) {
            const int ko = kt * 32 + hi * 8;
            const f16x8 xa = *(const f16x8*)&x16[l15][ko];
            const f16x8 ha = *(const f16x8*)&h16[l15][ko];
            az = MFMA(xa, Bx[0][kt], az);
            ar = MFMA(xa, Bx[1][kt], ar);
            ax = MFMA(xa, Bx[2][kt], ax);
            // rec-proj B-frags streamed from LDS (contiguous k in Wt^T)
            const f16x8 rz = *(const f16x8*)&Wt[j0 + l15][ko];
            const f16x8 rr_ = *(const f16x8*)&Wt[HID + j0 + l15][ko];
            const f16x8 rh = *(const f16x8*)&Wt[2 * HID + j0 + l15][ko];
            az = MFMA(ha, rz, az);
            ar = MFMA(ha, rr_, ar);
            ah = MFMA(ha, rh, ah);
        }

        // gates — fully lane-local (row = r0+i, col = j0+l15)
#pragma unroll
        for (int i = 0; i < 4; ++i) {
            const int tk = tok_sh[r0 + i];
            const float z  = 1.f / (1.f + __expf(-az[i]));
            const float rg = 1.f / (1.f + __expf(-ar[i]));
            const float e2 = __expf(2.f * (ax[i] + rg * ah[i]));
            const float hh = 1.f - 2.f / (e2 + 1.f);   // tanh
            const float hn = z * h[i] + (1.f - z) * hh;
            h[i] = (tk != 0) ? hn : h[i];
        }

        __syncthreads();   // all x16/h16 fragment reads done
#pragma unroll
        for (int i = 0; i < 4; ++i) h16[r0 + i][j0 + l15] = (f16)h[i];
        if (pf) {
            f16x4 xv; xv[0] = (f16)ev.x; xv[1] = (f16)ev.y; xv[2] = (f16)ev.z; xv[3] = (f16)ev.w;
            *(f16x4*)&x16[rr][c4] = xv;
            if ((tid & 31) == 0) tok_sh[rr] = tokA;
            tokA = tokB;
        }
        __syncthreads();   // x16/h16/tok_sh ready for s+1
    }

#pragma unroll
    for (int i = 0; i < 4; ++i)
        out[(size_t)(row0 + r0 + i) * HID + j0 + l15] = h[i];
}

extern "C" void kernel_launch(void* const* d_in, const int* in_sizes, int n_in,
                              void* d_out, int out_size, void* d_ws, size_t ws_size,
                              hipStream_t stream) {
    const int* inputs      = (const int*)d_in[0];
    const float* emb       = (const float*)d_in[1];
    const float* kernel    = (const float*)d_in[2];
    const float* rec_k     = (const float*)d_in[3];
    const float* bias      = (const float*)d_in[4];
    float* out             = (float*)d_out;
    gru_mfma<<<BATCH / ROWS, NTH, 0, stream>>>(inputs, emb, kernel, rec_k, bias, out);
}

// Round 13
// 290.096 us; speedup vs baseline: 63.1994x; 1.1755x over previous
//
#include <hip/hip_runtime.h>

#define BATCH 4096
#define SEQ   200
#define HID   128
#define ROWS  16
#define NTH   512
#define XPAD  136   // f16 per LDS row: stride 272B = 17*16 -> b128 reads spread all 8 bank-quads

typedef _Float16 f16;
typedef f16 f16x4 __attribute__((ext_vector_type(4)));
typedef f16 f16x8 __attribute__((ext_vector_type(8)));
typedef float f32x4 __attribute__((ext_vector_type(4)));

#define MFMA(a, b, c) __builtin_amdgcn_mfma_f32_16x16x32_f16((a), (b), (c), 0, 0, 0)

// Persistent GRU, v7: builtin MFMA (v6 verified), minus one barrier, minus 40%
// LDS traffic. Register budget (cap 128 @512thr, rounds 2-5): v6 used 88 with
// x-proj frags (48) in regs; headroom moves rec z+r frags (+32) in too ->
// only the rec h-gate streams from LDS Wt (35 KB). 12 b128/wave-step.
// Double-buffered x16/h16/tok (cur/next) -> ONE barrier per step: reads hit
// [cur], writes hit [next]; the end-of-step barrier is the only fence needed.
// grid 256 x 512thr: block = 16 batch rows; wave w = cols [16w,16w+16).
// Gates lane-local in D layout (col=lane&15, row=(lane>>4)*4+reg, m89).
__global__ __attribute__((amdgpu_flat_work_group_size(NTH, NTH)))
void gru_mfma(const int* __restrict__ inputs,
              const float* __restrict__ emb,
              const float* __restrict__ kernel,
              const float* __restrict__ rec_kernel,
              const float* __restrict__ bias,
              float* __restrict__ out)
{
    __shared__ __align__(16) f16 Wt[HID][XPAD];        // rec_kernel^T, h-gate cols only
    __shared__ __align__(16) f16 x16[2][ROWS][XPAD];   // f16 x_t, double-buffered
    __shared__ __align__(16) f16 h16[2][ROWS][XPAD];   // f16 h_{t-1}, double-buffered
    __shared__ int tok_sh[2][ROWS];
    __shared__ int ts_sh;

    const int tid  = threadIdx.x;
    const int lane = tid & 63;
    const int j0   = (tid >> 6) * 16;   // wave's column slice
    const int l15  = lane & 15;
    const int hi   = lane >> 4;         // 0..3
    const int r0   = hi * 4;            // D-layout row base
    const int row0 = blockIdx.x * ROWS;

    // int32-vs-int64 token stride, detected from data (int64 LE: odd words 0)
    if (tid == 0) { int any = 0; for (int i = 1; i < 128; i += 2) any |= inputs[i]; ts_sh = any ? 1 : 2; }

    // --- stage rec_kernel^T h-gate columns into LDS (one-time) ---
    for (int i = tid; i < HID * HID; i += NTH) {
        const int c = i & 127, k = i >> 7;
        Wt[c][k] = (f16)rec_kernel[(size_t)k * 384 + 256 + c];
    }

    // --- one-time register fragments: x-proj all 3 gates + rec z,r gates ---
    f16x8 Bx[3][4];            // [gate][ktile] : kernel
    f16x8 Brz[4], Brr[4];      // rec_kernel z,r
#pragma unroll
    for (int g = 0; g < 3; ++g)
#pragma unroll
        for (int kt = 0; kt < 4; ++kt) {
            f16x8 t;
#pragma unroll
            for (int e = 0; e < 8; ++e)
                t[e] = (f16)kernel[(size_t)(kt * 32 + hi * 8 + e) * 384 + g * HID + j0 + l15];
            Bx[g][kt] = t;
        }
#pragma unroll
    for (int kt = 0; kt < 4; ++kt) {
        f16x8 tz, tr;
#pragma unroll
        for (int e = 0; e < 8; ++e) {
            const size_t krow = (size_t)(kt * 32 + hi * 8 + e) * 384;
            tz[e] = (f16)rec_kernel[krow + j0 + l15];
            tr[e] = (f16)rec_kernel[krow + HID + j0 + l15];
        }
        Brz[kt] = tz; Brr[kt] = tr;
    }

    // biases for this lane's column (z,r combine input+rec bias; h split)
    const float bz  = bias[j0 + l15]       + bias[384 + j0 + l15];
    const float br  = bias[128 + j0 + l15] + bias[512 + j0 + l15];
    const float bxh = bias[256 + j0 + l15];
    const float brh = bias[640 + j0 + l15];

    f32x4 h = {0.f, 0.f, 0.f, 0.f};     // h state: rows r0..r0+3, col j0+l15

    __syncthreads();
    const int ts = ts_sh;

    const int rr = tid >> 5;            // gather: row 0..15
    const int c4 = (tid & 31) * 4;      // gather: 4-col group

    // --- prologue: stage x/tok for s=0 into buf 0, zero h16[0] ---
    {
        const int tok0 = inputs[((size_t)(row0 + rr) * SEQ + 0) * ts];
        if ((tid & 31) == 0) tok_sh[0][rr] = tok0;
        const float4 ev = *(const float4*)&emb[(size_t)tok0 * HID + c4];
        f16x4 xv; xv[0] = (f16)ev.x; xv[1] = (f16)ev.y; xv[2] = (f16)ev.z; xv[3] = (f16)ev.w;
        *(f16x4*)&x16[0][rr][c4] = xv;
        for (int i = tid; i < ROWS * XPAD; i += NTH) ((f16*)h16[0])[i] = (f16)0.f;
    }
    int tokA = inputs[((size_t)(row0 + rr) * SEQ + 1) * ts];   // token for s+1
    __syncthreads();

    for (int s = 0; s < SEQ; ++s) {
        const int cur = s & 1, nxt = cur ^ 1;
        const bool pf = (s + 1 < SEQ);
        float4 ev; int tokB = tokA;
        if (pf) {   // issue next-step gather early; lands in [nxt] after gates
            ev = *(const float4*)&emb[(size_t)tokA * HID + c4];
            const int s2 = (s + 2 < SEQ) ? (s + 2) : (SEQ - 1);
            tokB = inputs[((size_t)(row0 + rr) * SEQ + s2) * ts];
        }

        f32x4 az = {bz, bz, bz, bz}, ar = {br, br, br, br};
        f32x4 ax = {bxh, bxh, bxh, bxh}, ah = {brh, brh, brh, brh};
#pragma unroll
        for (int kt = 0; kt < 4; ++kt) {
            const int ko = kt * 32 + hi * 8;
            const f16x8 xa = *(const f16x8*)&x16[cur][l15][ko];
            const f16x8 ha = *(const f16x8*)&h16[cur][l15][ko];
            az = MFMA(xa, Bx[0][kt], az);
            ar = MFMA(xa, Bx[1][kt], ar);
            ax = MFMA(xa, Bx[2][kt], ax);
            az = MFMA(ha, Brz[kt], az);
            ar = MFMA(ha, Brr[kt], ar);
            const f16x8 rh = *(const f16x8*)&Wt[j0 + l15][ko];
            ah = MFMA(ha, rh, ah);
        }

        // gates — fully lane-local (row = r0+i, col = j0+l15)
#pragma unroll
        for (int i = 0; i < 4; ++i) {
            const int tk = tok_sh[cur][r0 + i];
            const float z  = 1.f / (1.f + __expf(-az[i]));
            const float rg = 1.f / (1.f + __expf(-ar[i]));
            const float e2 = __expf(2.f * (ax[i] + rg * ah[i]));
            const float hh = 1.f - 2.f / (e2 + 1.f);   // tanh
            const float hn = z * h[i] + (1.f - z) * hh;
            h[i] = (tk != 0) ? hn : h[i];
        }

        // writes go to [nxt] — no WAR vs other waves still reading [cur]
#pragma unroll
        for (int i = 0; i < 4; ++i) h16[nxt][r0 + i][j0 + l15] = (f16)h[i];
        if (pf) {
            f16x4 xv; xv[0] = (f16)ev.x; xv[1] = (f16)ev.y; xv[2] = (f16)ev.z; xv[3] = (f16)ev.w;
            *(f16x4*)&x16[nxt][rr][c4] = xv;
            if ((tid & 31) == 0) tok_sh[nxt][rr] = tokA;
            tokA = tokB;
        }
        __syncthreads();   // [nxt] ready; sole barrier per step
    }

#pragma unroll
    for (int i = 0; i < 4; ++i)
        out[(size_t)(row0 + r0 + i) * HID + j0 + l15] = h[i];
}

extern "C" void kernel_launch(void* const* d_in, const int* in_sizes, int n_in,
                              void* d_out, int out_size, void* d_ws, size_t ws_size,
                              hipStream_t stream) {
    const int* inputs      = (const int*)d_in[0];
    const float* emb       = (const float*)d_in[1];
    const float* kernel    = (const float*)d_in[2];
    const float* rec_k     = (const float*)d_in[3];
    const float* bias      = (const float*)d_in[4];
    float* out             = (float*)d_out;
    gru_mfma<<<BATCH / ROWS, NTH, 0, stream>>>(inputs, emb, kernel, rec_k, bias, out);
}

// Round 14
// 192.890 us; speedup vs baseline: 95.0483x; 1.5039x over previous
//
#include <hip/hip_runtime.h>

#define BATCH 4096
#define SEQ   200
#define HID   128
#define ROWS  16
#define NTH   512
#define XPAD  136   // f16 per LDS row: stride 272B = 17*16B, b128-aligned

typedef _Float16 f16;
typedef f16 f16x4 __attribute__((ext_vector_type(4)));
typedef f16 f16x8 __attribute__((ext_vector_type(8)));
typedef float f32x4 __attribute__((ext_vector_type(4)));

#define MFMA(a, b, c) __builtin_amdgcn_mfma_f32_16x16x32_f16((a), (b), (c), 0, 0, 0)

// Fast transcendentals: v_exp_f32 IS exp2 (1 instr), v_rcp_f32 is 1-instr
// reciprocal. Round 13's gate phase compiled IEEE-precise: 12 divisions/step
// expanded to div_scale/div_fmas/div_fixup (~10 instr each) + ocml exp (~6)
// = ~300 VALU instr/step of scaffolding -> VALUBusy 58% with MfmaUtil 21%.
__device__ __forceinline__ float fast_exp2(float x) {
#if defined(__has_builtin) && __has_builtin(__builtin_amdgcn_exp2f)
    return __builtin_amdgcn_exp2f(x);
#else
    float r; asm volatile("v_exp_f32 %0, %1\n\ts_nop 0" : "=v"(r) : "v"(x)); return r;
#endif
}
__device__ __forceinline__ float fast_rcp(float x) {
#if defined(__has_builtin) && __has_builtin(__builtin_amdgcn_rcpf)
    return __builtin_amdgcn_rcpf(x);
#else
    float r; asm volatile("v_rcp_f32 %0, %1\n\ts_nop 0" : "=v"(r) : "v"(x)); return r;
#endif
}
#define LOG2E  1.442695041f
#define LOG2E2 2.885390082f

// Persistent GRU, v8 = v7 + fast gate math.
// Register fragments: x-proj all 3 gates (48) + rec z,r (32); rec h-gate
// streams from LDS Wt (35 KB). Double-buffered x16/h16/tok -> ONE barrier
// per step. grid 256 x 512thr: block = 16 batch rows; wave w = cols
// [16w,16w+16). Gates lane-local in D layout (col=lane&15,
// row=(lane>>4)*4+reg, m89-verified); h state in 4 VGPRs/lane.
__global__ __attribute__((amdgpu_flat_work_group_size(NTH, NTH)))
void gru_mfma(const int* __restrict__ inputs,
              const float* __restrict__ emb,
              const float* __restrict__ kernel,
              const float* __restrict__ rec_kernel,
              const float* __restrict__ bias,
              float* __restrict__ out)
{
    __shared__ __align__(16) f16 Wt[HID][XPAD];        // rec_kernel^T, h-gate cols only
    __shared__ __align__(16) f16 x16[2][ROWS][XPAD];   // f16 x_t, double-buffered
    __shared__ __align__(16) f16 h16[2][ROWS][XPAD];   // f16 h_{t-1}, double-buffered
    __shared__ int tok_sh[2][ROWS];
    __shared__ int ts_sh;

    const int tid  = threadIdx.x;
    const int lane = tid & 63;
    const int j0   = (tid >> 6) * 16;   // wave's column slice
    const int l15  = lane & 15;
    const int hi   = lane >> 4;         // 0..3
    const int r0   = hi * 4;            // D-layout row base
    const int row0 = blockIdx.x * ROWS;

    // int32-vs-int64 token stride, detected from data (int64 LE: odd words 0)
    if (tid == 0) { int any = 0; for (int i = 1; i < 128; i += 2) any |= inputs[i]; ts_sh = any ? 1 : 2; }

    // --- stage rec_kernel^T h-gate columns into LDS (one-time) ---
    for (int i = tid; i < HID * HID; i += NTH) {
        const int c = i & 127, k = i >> 7;
        Wt[c][k] = (f16)rec_kernel[(size_t)k * 384 + 256 + c];
    }

    // --- one-time register fragments: x-proj all 3 gates + rec z,r gates ---
    f16x8 Bx[3][4];            // [gate][ktile] : kernel
    f16x8 Brz[4], Brr[4];      // rec_kernel z,r
#pragma unroll
    for (int g = 0; g < 3; ++g)
#pragma unroll
        for (int kt = 0; kt < 4; ++kt) {
            f16x8 t;
#pragma unroll
            for (int e = 0; e < 8; ++e)
                t[e] = (f16)kernel[(size_t)(kt * 32 + hi * 8 + e) * 384 + g * HID + j0 + l15];
            Bx[g][kt] = t;
        }
#pragma unroll
    for (int kt = 0; kt < 4; ++kt) {
        f16x8 tz, tr;
#pragma unroll
        for (int e = 0; e < 8; ++e) {
            const size_t krow = (size_t)(kt * 32 + hi * 8 + e) * 384;
            tz[e] = (f16)rec_kernel[krow + j0 + l15];
            tr[e] = (f16)rec_kernel[krow + HID + j0 + l15];
        }
        Brz[kt] = tz; Brr[kt] = tr;
    }

    // biases for this lane's column (z,r combine input+rec bias; h split)
    const float bz  = bias[j0 + l15]       + bias[384 + j0 + l15];
    const float br  = bias[128 + j0 + l15] + bias[512 + j0 + l15];
    const float bxh = bias[256 + j0 + l15];
    const float brh = bias[640 + j0 + l15];

    f32x4 h = {0.f, 0.f, 0.f, 0.f};     // h state: rows r0..r0+3, col j0+l15

    __syncthreads();
    const int ts = ts_sh;

    const int rr = tid >> 5;            // gather: row 0..15
    const int c4 = (tid & 31) * 4;      // gather: 4-col group

    // --- prologue: stage x/tok for s=0 into buf 0, zero h16[0] ---
    {
        const int tok0 = inputs[((size_t)(row0 + rr) * SEQ + 0) * ts];
        if ((tid & 31) == 0) tok_sh[0][rr] = tok0;
        const float4 ev = *(const float4*)&emb[(size_t)tok0 * HID + c4];
        f16x4 xv; xv[0] = (f16)ev.x; xv[1] = (f16)ev.y; xv[2] = (f16)ev.z; xv[3] = (f16)ev.w;
        *(f16x4*)&x16[0][rr][c4] = xv;
        for (int i = tid; i < ROWS * XPAD; i += NTH) ((f16*)h16[0])[i] = (f16)0.f;
    }
    int tokA = inputs[((size_t)(row0 + rr) * SEQ + 1) * ts];   // token for s+1
    __syncthreads();

    for (int s = 0; s < SEQ; ++s) {
        const int cur = s & 1, nxt = cur ^ 1;
        const bool pf = (s + 1 < SEQ);
        float4 ev; int tokB = tokA;
        if (pf) {   // issue next-step gather early; lands in [nxt] after gates
            ev = *(const float4*)&emb[(size_t)tokA * HID + c4];
            const int s2 = (s + 2 < SEQ) ? (s + 2) : (SEQ - 1);
            tokB = inputs[((size_t)(row0 + rr) * SEQ + s2) * ts];
        }

        f32x4 az = {bz, bz, bz, bz}, ar = {br, br, br, br};
        f32x4 ax = {bxh, bxh, bxh, bxh}, ah = {brh, brh, brh, brh};
#pragma unroll
        for (int kt = 0; kt < 4; ++kt) {
            const int ko = kt * 32 + hi * 8;
            const f16x8 xa = *(const f16x8*)&x16[cur][l15][ko];
            const f16x8 ha = *(const f16x8*)&h16[cur][l15][ko];
            az = MFMA(xa, Bx[0][kt], az);
            ar = MFMA(xa, Bx[1][kt], ar);
            ax = MFMA(xa, Bx[2][kt], ax);
            az = MFMA(ha, Brz[kt], az);
            ar = MFMA(ha, Brr[kt], ar);
            const f16x8 rh = *(const f16x8*)&Wt[j0 + l15][ko];
            ah = MFMA(ha, rh, ah);
        }

        // gates — lane-local, raw-rate transcendentals
#pragma unroll
        for (int i = 0; i < 4; ++i) {
            const int tk = tok_sh[cur][r0 + i];
            const float z  = fast_rcp(1.f + fast_exp2(-LOG2E  * az[i]));
            const float rg = fast_rcp(1.f + fast_exp2(-LOG2E  * ar[i]));
            const float u  = ax[i] + rg * ah[i];
            const float hh = 1.f - 2.f * fast_rcp(1.f + fast_exp2(LOG2E2 * u));  // tanh(u)
            const float hn = z * h[i] + (1.f - z) * hh;
            h[i] = (tk != 0) ? hn : h[i];
        }

        // writes go to [nxt] — no WAR vs other waves still reading [cur]
#pragma unroll
        for (int i = 0; i < 4; ++i) h16[nxt][r0 + i][j0 + l15] = (f16)h[i];
        if (pf) {
            f16x4 xv; xv[0] = (f16)ev.x; xv[1] = (f16)ev.y; xv[2] = (f16)ev.z; xv[3] = (f16)ev.w;
            *(f16x4*)&x16[nxt][rr][c4] = xv;
            if ((tid & 31) == 0) tok_sh[nxt][rr] = tokA;
            tokA = tokB;
        }
        __syncthreads();   // [nxt] ready; sole barrier per step
    }

#pragma unroll
    for (int i = 0; i < 4; ++i)
        out[(size_t)(row0 + r0 + i) * HID + j0 + l15] = h[i];
}

extern "C" void kernel_launch(void* const* d_in, const int* in_sizes, int n_in,
                              void* d_out, int out_size, void* d_ws, size_t ws_size,
                              hipStream_t stream) {
    const int* inputs      = (const int*)d_in[0];
    const float* emb       = (const float*)d_in[1];
    const float* kernel    = (const float*)d_in[2];
    const float* rec_k     = (const float*)d_in[3];
    const float* bias      = (const float*)d_in[4];
    float* out             = (float*)d_out;
    gru_mfma<<<BATCH / ROWS, NTH, 0, stream>>>(inputs, emb, kernel, rec_k, bias, out);
}

// Round 15
// 182.460 us; speedup vs baseline: 100.4817x; 1.0572x over previous
//
#include <hip/hip_runtime.h>

#define BATCH 4096
#define SEQ   200
#define HID   128
#define ROWS  16
#define NTH   512

typedef _Float16 f16;
typedef f16 f16x4 __attribute__((ext_vector_type(4)));
typedef f16 f16x8 __attribute__((ext_vector_type(8)));
typedef float f32x4 __attribute__((ext_vector_type(4)));

#define MFMA(a, b, c) __builtin_amdgcn_mfma_f32_16x16x32_f16((a), (b), (c), 0, 0, 0)

__device__ __forceinline__ float fast_exp2(float x) {
#if defined(__has_builtin) && __has_builtin(__builtin_amdgcn_exp2f)
    return __builtin_amdgcn_exp2f(x);
#else
    float r; asm volatile("v_exp_f32 %0, %1\n\ts_nop 0" : "=v"(r) : "v"(x)); return r;
#endif
}
__device__ __forceinline__ float fast_rcp(float x) {
#if defined(__has_builtin) && __has_builtin(__builtin_amdgcn_rcpf)
    return __builtin_amdgcn_rcpf(x);
#else
    float r; asm volatile("v_rcp_f32 %0, %1\n\ts_nop 0" : "=v"(r) : "v"(x)); return r;
#endif
}
#define LOG2E  1.442695041f
#define LOG2E2 2.885390082f

// Persistent GRU, v9 = v8 + fragment-linear LDS (zero read conflicts) + gate
// scales folded into weights.
// Round 14 counters: conflicts 2.0e7 = 391 cyc/CU-step — XPAD-136 strides put
// every b128 A-frag read on 16B quads indexed by (l15+hi)%8 -> 8-way. Fix:
// store tiles in MFMA fragment order [kt][lane=hi*16+l15][8 f16]; each wave's
// b128 gang then reads contiguous 1024 B (lane i -> unit i) = conflict-free,
// and read addressing is base + lane*16 + kt*1024(imm).
// Scale folding: z/r weight frags & biases pre-scaled by -log2(e), h-gate by
// +2log2(e) -> sigmoid = rcp(1+exp2(acc)), tanh arg comes out of MFMA scaled.
// Layout recap: block = 16 batch rows, wave w = cols [16w,16w+16); x-proj
// frags (48 regs) + rec z/r frags (32 regs) resident; rec h-gate streams from
// LDS Wtf (32 KB, per-wave fragment order). Double-buffered xf/hf/tok -> one
// barrier/step. D layout col=lane&15, row=(lane>>4)*4+reg (m89-verified).
__global__ __attribute__((amdgpu_flat_work_group_size(NTH, NTH)))
void gru_mfma(const int* __restrict__ inputs,
              const float* __restrict__ emb,
              const float* __restrict__ kernel,
              const float* __restrict__ rec_kernel,
              const float* __restrict__ bias,
              float* __restrict__ out)
{
    // fragment-linear tiles: flat f16 index ((buf_or_w*4 + kt)*64 + unit)*8 + e
    __shared__ __align__(16) f16 Wtf[8][4][64][8];   // rec h-gate, per-wave frags, 32 KB
    __shared__ __align__(16) f16 xf[2][4][64][8];    // x_t frags, dbuf, 8 KB
    __shared__ __align__(16) f16 hf[2][4][64][8];    // h_{t-1} frags, dbuf, 8 KB
    __shared__ int tok_sh[2][ROWS];
    __shared__ int ts_sh;

    const int tid  = threadIdx.x;
    const int lane = tid & 63;
    const int wv   = tid >> 6;          // wave id 0..7
    const int j0   = wv * 16;           // wave's column slice
    const int l15  = lane & 15;
    const int hi   = lane >> 4;         // 0..3
    const int r0   = hi * 4;            // D-layout row base
    const int row0 = blockIdx.x * ROWS;

    // int32-vs-int64 token stride, detected from data (int64 LE: odd words 0)
    if (tid == 0) { int any = 0; for (int i = 1; i < 128; i += 2) any |= inputs[i]; ts_sh = any ? 1 : 2; }

    // --- stage rec_kernel h-gate into LDS in fragment order, pre-scaled ---
    for (int i = tid; i < 8 * 4 * 64 * 8; i += NTH) {
        const int e = i & 7, ln = (i >> 3) & 63, kt = (i >> 9) & 3, w = i >> 11;
        const int c = w * 16 + (ln & 15);
        const int k = kt * 32 + (ln >> 4) * 8 + e;
        ((f16*)Wtf)[i] = (f16)(LOG2E2 * rec_kernel[(size_t)k * 384 + 256 + c]);
    }

    // --- one-time register fragments (scales folded) ---
    f16x8 Bx[3][4];            // kernel: z,r scaled -LOG2E; h scaled +LOG2E2
    f16x8 Brz[4], Brr[4];      // rec_kernel z,r scaled -LOG2E
    const float gsc[3] = { -LOG2E, -LOG2E, LOG2E2 };
#pragma unroll
    for (int g = 0; g < 3; ++g)
#pragma unroll
        for (int kt = 0; kt < 4; ++kt) {
            f16x8 t;
#pragma unroll
            for (int e = 0; e < 8; ++e)
                t[e] = (f16)(gsc[g] * kernel[(size_t)(kt * 32 + hi * 8 + e) * 384 + g * HID + j0 + l15]);
            Bx[g][kt] = t;
        }
#pragma unroll
    for (int kt = 0; kt < 4; ++kt) {
        f16x8 tz, tr;
#pragma unroll
        for (int e = 0; e < 8; ++e) {
            const size_t krow = (size_t)(kt * 32 + hi * 8 + e) * 384;
            tz[e] = (f16)(-LOG2E * rec_kernel[krow + j0 + l15]);
            tr[e] = (f16)(-LOG2E * rec_kernel[krow + HID + j0 + l15]);
        }
        Brz[kt] = tz; Brr[kt] = tr;
    }

    // biases for this lane's column, same folding
    const float bz  = -LOG2E * (bias[j0 + l15]       + bias[384 + j0 + l15]);
    const float br  = -LOG2E * (bias[128 + j0 + l15] + bias[512 + j0 + l15]);
    const float bxh =  LOG2E2 * bias[256 + j0 + l15];
    const float brh =  LOG2E2 * bias[640 + j0 + l15];

    f32x4 h = {0.f, 0.f, 0.f, 0.f};     // h state: rows r0..r0+3, col j0+l15

    // h-write fragment address components (this lane's column c = j0+l15)
    const int cw  = j0 + l15;
    const int hwi = ((cw >> 5) * 64 + ((cw >> 3) & 3) * 16 + r0) * 8 + (cw & 7);  // + i*8 per row

    __syncthreads();
    const int ts = ts_sh;

    const int rr = tid >> 5;            // gather: row 0..15
    const int c4 = (tid & 31) * 4;      // gather: 4 consecutive k
    const int xwi = ((c4 >> 5) * 64 + ((c4 >> 3) & 3) * 16 + rr) * 8 + (c4 & 7); // x-stage frag idx

    // --- prologue: stage x/tok for s=0 into buf 0, zero hf[0] ---
    {
        const int tok0 = inputs[((size_t)(row0 + rr) * SEQ + 0) * ts];
        if ((tid & 31) == 0) tok_sh[0][rr] = tok0;
        const float4 ev = *(const float4*)&emb[(size_t)tok0 * HID + c4];
        f16x4 xv; xv[0] = (f16)ev.x; xv[1] = (f16)ev.y; xv[2] = (f16)ev.z; xv[3] = (f16)ev.w;
        *(f16x4*)&((f16*)xf)[xwi] = xv;                 // buf 0
        for (int i = tid; i < 4 * 64 * 8; i += NTH) ((f16*)hf)[i] = (f16)0.f;  // hf[0]
    }
    int tokA = inputs[((size_t)(row0 + rr) * SEQ + 1) * ts];   // token for s+1
    __syncthreads();

    for (int s = 0; s < SEQ; ++s) {
        const int cur = s & 1, nxt = cur ^ 1;
        const bool pf = (s + 1 < SEQ);
        float4 ev; int tokB = tokA;
        if (pf) {   // issue next-step gather early; lands in [nxt] after gates
            ev = *(const float4*)&emb[(size_t)tokA * HID + c4];
            const int s2 = (s + 2 < SEQ) ? (s + 2) : (SEQ - 1);
            tokB = inputs[((size_t)(row0 + rr) * SEQ + s2) * ts];
        }

        f32x4 az = {bz, bz, bz, bz}, ar = {br, br, br, br};
        f32x4 ax = {bxh, bxh, bxh, bxh}, ah = {brh, brh, brh, brh};
#pragma unroll
        for (int kt = 0; kt < 4; ++kt) {
            const f16x8 xa = *(const f16x8*)&xf[cur][kt][lane][0];
            const f16x8 ha = *(const f16x8*)&hf[cur][kt][lane][0];
            az = MFMA(xa, Bx[0][kt], az);
            ar = MFMA(xa, Bx[1][kt], ar);
            ax = MFMA(xa, Bx[2][kt], ax);
            az = MFMA(ha, Brz[kt], az);
            ar = MFMA(ha, Brr[kt], ar);
            const f16x8 rh = *(const f16x8*)&Wtf[wv][kt][lane][0];
            ah = MFMA(ha, rh, ah);
        }

        // gates — lane-local; scales pre-folded into the accumulators
#pragma unroll
        for (int i = 0; i < 4; ++i) {
            const int tk = tok_sh[cur][r0 + i];
            const float z  = fast_rcp(1.f + fast_exp2(az[i]));
            const float rg = fast_rcp(1.f + fast_exp2(ar[i]));
            const float u  = ax[i] + rg * ah[i];              // already 2*log2e-scaled
            const float hh = 1.f - 2.f * fast_rcp(1.f + fast_exp2(u));
            const float hn = hh + z * (h[i] - hh);
            h[i] = (tk != 0) ? hn : h[i];
        }

        // scatter h into fragment order for [nxt]
        {
            f16* hp = &((f16*)hf)[nxt * 4 * 64 * 8 + hwi];
#pragma unroll
            for (int i = 0; i < 4; ++i) hp[i * 8] = (f16)h[i];
        }
        if (pf) {
            f16x4 xv; xv[0] = (f16)ev.x; xv[1] = (f16)ev.y; xv[2] = (f16)ev.z; xv[3] = (f16)ev.w;
            *(f16x4*)&((f16*)xf)[nxt * 4 * 64 * 8 + xwi] = xv;
            if ((tid & 31) == 0) tok_sh[nxt][rr] = tokA;
            tokA = tokB;
        }
        __syncthreads();   // [nxt] ready; sole barrier per step
    }

#pragma unroll
    for (int i = 0; i < 4; ++i)
        out[(size_t)(row0 + r0 + i) * HID + j0 + l15] = h[i];
}

extern "C" void kernel_launch(void* const* d_in, const int* in_sizes, int n_in,
                              void* d_out, int out_size, void* d_ws, size_t ws_size,
                              hipStream_t stream) {
    const int* inputs      = (const int*)d_in[0];
    const float* emb       = (const float*)d_in[1];
    const float* kernel    = (const float*)d_in[2];
    const float* rec_k     = (const float*)d_in[3];
    const float* bias      = (const float*)d_in[4];
    float* out             = (float*)d_out;
    gru_mfma<<<BATCH / ROWS, NTH, 0, stream>>>(inputs, emb, kernel, rec_k, bias, out);
}